// Round 1
// baseline (123.829 us; speedup 1.0000x reference)
//
#include <hip/hip_runtime.h>

// LocalCrossCorrelation2D: 9x9 zero-padded box-filter NCC loss.
// I,J: [32,1,512,512] fp32. out: [32] fp32 = 1 - mean(cc).
//
// Design: one wave64 = one full-width row strip (512 cols = 64 lanes x 8 cols).
// Vertical 9-window via per-column running sums (slide: +row(y+5), -row(y-4),
// old row re-loaded from cache). Horizontal 9-window via 16-entry register
// window (8 own cols + 4 left halo by shfl_up + 4 right halo by shfl_down,
// zeroed at true image edges) with horizontal sliding across the 8 outputs.
// No LDS, no barriers. 8 rows/wave -> 2048 waves -> 512 blocks of 256.

#define IMG_H 512
#define IMG_W 512
#define NBATCH 32
#define RPW 8                    // output rows per wave
#define STRIPS_PER_IMG (IMG_H / RPW)   // 64

__global__ void lcc_init(float* __restrict__ out) {
    int i = threadIdx.x;
    if (i < NBATCH) out[i] = 1.0f;
}

__global__ __launch_bounds__(256, 2) void lcc_main(const float* __restrict__ I,
                                                   const float* __restrict__ J,
                                                   float* __restrict__ out) {
    const int tid  = threadIdx.x;
    const int lane = tid & 63;
    const int wv   = tid >> 6;
    const int strip = blockIdx.x * 4 + wv;          // 0..2047
    const int b  = strip >> 6;                      // 64 strips per image
    const int y0 = (strip & 63) * RPW;
    const int x0 = lane * 8;

    const float* __restrict__ Ib = I + (size_t)b * IMG_H * IMG_W;
    const float* __restrict__ Jb = J + (size_t)b * IMG_H * IMG_W;

    // vertical running sums for this lane's 8 columns
    float sI[8]  = {0.f,0.f,0.f,0.f,0.f,0.f,0.f,0.f};
    float sJ[8]  = {0.f,0.f,0.f,0.f,0.f,0.f,0.f,0.f};
    float sII[8] = {0.f,0.f,0.f,0.f,0.f,0.f,0.f,0.f};
    float sJJ[8] = {0.f,0.f,0.f,0.f,0.f,0.f,0.f,0.f};
    float sIJ[8] = {0.f,0.f,0.f,0.f,0.f,0.f,0.f,0.f};

    auto add_row = [&](int y) {
        const float4* pI = reinterpret_cast<const float4*>(Ib + y * IMG_W + x0);
        const float4* pJ = reinterpret_cast<const float4*>(Jb + y * IMG_W + x0);
        float4 i0 = pI[0], i1 = pI[1];
        float4 j0 = pJ[0], j1 = pJ[1];
        float iv[8] = {i0.x,i0.y,i0.z,i0.w,i1.x,i1.y,i1.z,i1.w};
        float jv[8] = {j0.x,j0.y,j0.z,j0.w,j1.x,j1.y,j1.z,j1.w};
        #pragma unroll
        for (int c = 0; c < 8; ++c) {
            sI[c]  += iv[c];
            sJ[c]  += jv[c];
            sII[c]  = fmaf(iv[c], iv[c], sII[c]);
            sJJ[c]  = fmaf(jv[c], jv[c], sJJ[c]);
            sIJ[c]  = fmaf(iv[c], jv[c], sIJ[c]);
        }
    };
    auto sub_row = [&](int y) {
        const float4* pI = reinterpret_cast<const float4*>(Ib + y * IMG_W + x0);
        const float4* pJ = reinterpret_cast<const float4*>(Jb + y * IMG_W + x0);
        float4 i0 = pI[0], i1 = pI[1];
        float4 j0 = pJ[0], j1 = pJ[1];
        float iv[8] = {i0.x,i0.y,i0.z,i0.w,i1.x,i1.y,i1.z,i1.w};
        float jv[8] = {j0.x,j0.y,j0.z,j0.w,j1.x,j1.y,j1.z,j1.w};
        #pragma unroll
        for (int c = 0; c < 8; ++c) {
            sI[c]  -= iv[c];
            sJ[c]  -= jv[c];
            sII[c]  = fmaf(-iv[c], iv[c], sII[c]);
            sJJ[c]  = fmaf(-jv[c], jv[c], sJJ[c]);
            sIJ[c]  = fmaf(-iv[c], jv[c], sIJ[c]);
        }
    };

    // warm-up: window rows y0-4 .. y0+4 (zero padding below row 0)
    for (int y = y0 - 4; y <= y0 + 4; ++y)
        if (y >= 0 && y < IMG_H) add_row(y);

    const float inv81 = 1.0f / 81.0f;
    const float EPSV  = 3.0590232050182579e-07f;   // e^-15
    float local = 0.0f;

    for (int y = y0; y < y0 + RPW; ++y) {
        // build 16-entry horizontal windows: [L4..L7 | own 0..7 | R0..R3]
        float vI[16], vJ[16], vII[16], vJJ[16], vIJ[16];
        #pragma unroll
        for (int c = 0; c < 8; ++c) {
            vI[4+c] = sI[c]; vJ[4+c] = sJ[c]; vII[4+c] = sII[c];
            vJJ[4+c] = sJJ[c]; vIJ[4+c] = sIJ[c];
        }
        #pragma unroll
        for (int c = 0; c < 4; ++c) {
            float a;
            a = __shfl_up(sI[4+c], 1);   vI[c]  = lane ? a : 0.f;
            a = __shfl_up(sJ[4+c], 1);   vJ[c]  = lane ? a : 0.f;
            a = __shfl_up(sII[4+c], 1);  vII[c] = lane ? a : 0.f;
            a = __shfl_up(sJJ[4+c], 1);  vJJ[c] = lane ? a : 0.f;
            a = __shfl_up(sIJ[4+c], 1);  vIJ[c] = lane ? a : 0.f;
            a = __shfl_down(sI[c], 1);   vI[12+c]  = (lane < 63) ? a : 0.f;
            a = __shfl_down(sJ[c], 1);   vJ[12+c]  = (lane < 63) ? a : 0.f;
            a = __shfl_down(sII[c], 1);  vII[12+c] = (lane < 63) ? a : 0.f;
            a = __shfl_down(sJJ[c], 1);  vJJ[12+c] = (lane < 63) ? a : 0.f;
            a = __shfl_down(sIJ[c], 1);  vIJ[12+c] = (lane < 63) ? a : 0.f;
        }
        // horizontal 9-sum for output col k uses entries k..k+8
        float hI = 0.f, hJ = 0.f, hII = 0.f, hJJ = 0.f, hIJ = 0.f;
        #pragma unroll
        for (int i = 0; i < 9; ++i) {
            hI += vI[i]; hJ += vJ[i]; hII += vII[i]; hJJ += vJJ[i]; hIJ += vIJ[i];
        }
        #pragma unroll
        for (int k = 0; k < 8; ++k) {
            float cross = fmaf(hI * hJ, -inv81, hIJ);
            float Iv    = fmaf(hI * hI, -inv81, hII);
            float Jv    = fmaf(hJ * hJ, -inv81, hJJ);
            float p  = Iv * Jv;
            bool  nz = p > EPSV;
            float c2 = nz ? cross : 1.0f;
            float p2 = nz ? p : 1.0f;
            local += (c2 * c2) * __builtin_amdgcn_rcpf(p2 + EPSV);
            if (k < 7) {
                hI  += vI[k+9]  - vI[k];
                hJ  += vJ[k+9]  - vJ[k];
                hII += vII[k+9] - vII[k];
                hJJ += vJJ[k+9] - vJJ[k];
                hIJ += vIJ[k+9] - vIJ[k];
            }
        }
        // slide vertical window to row y+1
        if (y + 1 < y0 + RPW) {
            int ya = y + 5, yr = y - 4;
            if (ya < IMG_H) add_row(ya);
            if (yr >= 0)    sub_row(yr);
        }
    }

    // wave reduction, then one atomic per wave
    #pragma unroll
    for (int off = 32; off > 0; off >>= 1) local += __shfl_down(local, off);
    if (lane == 0)
        atomicAdd(out + b, local * (-1.0f / (float)(IMG_H * IMG_W)));
}

extern "C" void kernel_launch(void* const* d_in, const int* in_sizes, int n_in,
                              void* d_out, int out_size, void* d_ws, size_t ws_size,
                              hipStream_t stream) {
    const float* I = (const float*)d_in[0];
    const float* J = (const float*)d_in[1];
    float* out = (float*)d_out;

    lcc_init<<<1, 64, 0, stream>>>(out);
    const int total_strips = NBATCH * STRIPS_PER_IMG;   // 2048 waves
    lcc_main<<<total_strips / 4, 256, 0, stream>>>(I, J, out);
}